// Round 1
// baseline (209.798 us; speedup 1.0000x reference)
//
#include <hip/hip_runtime.h>

#define TPB 512
#define APB 512
#define NPOS 288
#define NCH 3
#define CHUNK 96
#define PSTRIDE 1056  // 32 c * 33 floats (16 mu-acc, 16 var-acc, 1 rsum)

// ---------------------------------------------------------------------------
// Pipeline version: 3 accumulate kernels (one per EM iteration) + finalize.
// Grid 864 = 288 positions x 3 chunks of 96 n. Kernel boundaries provide the
// per-iteration global sync; chunk partials live in d_ws (no atomics).
// ---------------------------------------------------------------------------

template<int IT>
__global__ __launch_bounds__(APB, 4) void caps_acc(
    const float* __restrict__ xg,
    const float* __restrict__ ag,
    const float* __restrict__ wg,
    const float* __restrict__ bu,
    const float* __restrict__ ba,
    const float* __restrict__ pin,   // previous-iteration partials (IT>0)
    float* __restrict__ pout)        // this-iteration partials
{
    __shared__ __align__(16) float pose_s[CHUNK * 16];   // 96 n x 16 p
    __shared__ float a_s[CHUNK];
    __shared__ __align__(16) float scratch[8 * 32 * 33]; // 8 waves x 32 c x 33
    __shared__ float rsum_part[8 * 32];
    __shared__ float mu_tab[512];
    __shared__ float i2s_tab[512];
    __shared__ float Kc_tab[32];

    const int tid = threadIdx.x;
    const int blk = blockIdx.x;
    const int pos = blk / NCH;
    const int ch  = blk - pos * NCH;     // kh row of the 3x3 window
    const int bb  = pos / 36;
    const int rem = pos % 36;
    const int yy  = rem / 6;
    const int xx  = rem % 6;

    // ---- stage this chunk's pose slice (window row kh=ch, kw=0..2) ----
    #pragma unroll
    for (int j = 0; j < 3; ++j) {
        const float* src =
            xg + (size_t)((((bb * 14) + (2 * yy + ch)) * 14 + (2 * xx + j)) * 32) * 16;
        pose_s[j * 512 + tid] = src[tid];
    }
    if (IT == 0) {
        if (tid < CHUNK) {
            const int j = tid >> 5, bi = tid & 31;
            a_s[tid] = ag[(size_t)(((bb * 14) + (2 * yy + ch)) * 14 + (2 * xx + j)) * 32 + bi];
        }
    }

    const int fc = tid >> 4, fp = tid & 15;
    if (IT > 0) {
        // ---- redundant finalize of previous iteration from global partials ----
        const float* q0 = pin + (size_t)pos * (NCH * PSTRIDE) + fc * 33;
        float ms = 0.f, vs = 0.f, rsc = 0.f;
        #pragma unroll
        for (int cc = 0; cc < NCH; ++cc) {
            const float* q = q0 + cc * PSTRIDE;
            ms  += q[fp];
            vs  += q[16 + fp];
            rsc += q[32];
        }
        const float inv = 1.f / (rsc + 1e-6f);
        const float S   = rsc * inv;
        const float mu  = ms * inv;
        const float sig = vs * inv - mu * mu * (2.f - S) + 1e-6f;
        const float lg  = __logf(sig);
        float lgs = lg;
        #pragma unroll
        for (int msk = 8; msk >= 1; msk >>= 1) lgs += __shfl_xor(lgs, msk);
        const float cost = rsc * (16.f * bu[fc] + 0.5f * lgs);
        const float ao   = 1.f / (1.f + __expf(-0.001f * (ba[fc] - cost)));
        mu_tab[tid]  = mu;            // tid == fc*16+fp
        i2s_tab[tid] = 0.5f / sig;
        if (fp == 0) Kc_tab[fc] = 0.5f * lgs - __logf(ao);
    }
    __syncthreads();

    const int c    = tid & 31;   // capsule-out index
    const int s    = tid >> 5;   // n-slice 0..15 (6 n each)
    const int lane = tid & 63;
    const int wv   = tid >> 6;
    const float4* wp = (const float4*)wg;

    float mu_c[16], i2s_c[16], Kc = 0.f;
    if (IT > 0) {
        #pragma unroll
        for (int p = 0; p < 16; ++p) {
            mu_c[p]  = mu_tab[c * 16 + p];
            i2s_c[p] = i2s_tab[c * 16 + p];
        }
        Kc = Kc_tab[c];
    }
    float macc[16], vacc[16], rs = 0.f;
    #pragma unroll
    for (int p = 0; p < 16; ++p) { macc[p] = 0.f; vacc[p] = 0.f; }

    // ---- fused E+M pass over this thread's 6 n values ----
    for (int k = 0; k < 6; ++k) {
        const int nl = s * 6 + k;            // 0..95 within chunk
        const int n  = ch * CHUNK + nl;      // global n
        const float4* pp = (const float4*)&pose_s[nl << 4];
        float pf[16];
        float4 q;
        q = pp[0]; pf[0]=q.x;  pf[1]=q.y;  pf[2]=q.z;  pf[3]=q.w;
        q = pp[1]; pf[4]=q.x;  pf[5]=q.y;  pf[6]=q.z;  pf[7]=q.w;
        q = pp[2]; pf[8]=q.x;  pf[9]=q.y;  pf[10]=q.z; pf[11]=q.w;
        q = pp[3]; pf[12]=q.x; pf[13]=q.y; pf[14]=q.z; pf[15]=q.w;
        const int wbase = (n * 32 + c) * 4;
        float wf[16];
        float4 w0 = wp[wbase + 0]; wf[0]=w0.x;  wf[1]=w0.y;  wf[2]=w0.z;  wf[3]=w0.w;
        float4 w1 = wp[wbase + 1]; wf[4]=w1.x;  wf[5]=w1.y;  wf[6]=w1.z;  wf[7]=w1.w;
        float4 w2 = wp[wbase + 2]; wf[8]=w2.x;  wf[9]=w2.y;  wf[10]=w2.z; wf[11]=w2.w;
        float4 w3 = wp[wbase + 3]; wf[12]=w3.x; wf[13]=w3.y; wf[14]=w3.z; wf[15]=w3.w;
        float v[16];
        #pragma unroll
        for (int i = 0; i < 4; ++i)
            #pragma unroll
            for (int l = 0; l < 4; ++l)
                v[i*4+l] = pf[i*4+0] * wf[0*4+l] + pf[i*4+1] * wf[1*4+l]
                         + pf[i*4+2] * wf[2*4+l] + pf[i*4+3] * wf[3*4+l];
        float r;
        if (IT == 0) {
            r = a_s[nl] * 0.03125f;  // (1/C) * a_in
        } else {
            // tree-reduced t = sum_p (v-mu)^2 * i2s
            float t0 = 0.f, t1 = 0.f, t2 = 0.f, t3 = 0.f;
            #pragma unroll
            for (int p = 0; p < 16; p += 4) {
                float d0 = v[p]   - mu_c[p];   t0 = fmaf(d0*d0, i2s_c[p],   t0);
                float d1 = v[p+1] - mu_c[p+1]; t1 = fmaf(d1*d1, i2s_c[p+1], t1);
                float d2 = v[p+2] - mu_c[p+2]; t2 = fmaf(d2*d2, i2s_c[p+2], t2);
                float d3 = v[p+3] - mu_c[p+3]; t3 = fmaf(d3*d3, i2s_c[p+3], t3);
            }
            float lnap = -((t0 + t1) + (t2 + t3)) - Kc;
            float m = lnap;
            #pragma unroll
            for (int msk = 16; msk >= 1; msk >>= 1) m = fmaxf(m, __shfl_xor(m, msk));
            float e = __expf(lnap - m);
            float sum = e;
            #pragma unroll
            for (int msk = 16; msk >= 1; msk >>= 1) sum += __shfl_xor(sum, msk);
            r = e / sum;
        }
        rs += r;
        #pragma unroll
        for (int p = 0; p < 16; ++p) {
            float rv = r * v[p];
            macc[p] += rv;
            vacc[p] = fmaf(rv, v[p], vacc[p]);
        }
    }

    // ---- reduce the 16 n-slices: shfl pairs, then LDS across 8 waves ----
    #pragma unroll
    for (int p = 0; p < 16; ++p) {
        macc[p] += __shfl_xor(macc[p], 32);
        vacc[p] += __shfl_xor(vacc[p], 32);
    }
    rs += __shfl_xor(rs, 32);
    if (lane < 32) {
        const int base = (wv * 32 + lane) * 33;
        #pragma unroll
        for (int p = 0; p < 16; ++p) {
            scratch[base + p]      = macc[p];
            scratch[base + 16 + p] = vacc[p];
        }
        rsum_part[wv * 32 + lane] = rs;
    }
    __syncthreads();

    // ---- block-level sum -> write chunk partials (not finalized) ----
    float ms = 0.f, vs = 0.f, rsc = 0.f;
    #pragma unroll
    for (int w = 0; w < 8; ++w) {
        ms  += scratch[(w * 32 + fc) * 33 + fp];
        vs  += scratch[(w * 32 + fc) * 33 + 16 + fp];
        rsc += rsum_part[w * 32 + fc];
    }
    float* po = pout + (size_t)(pos * NCH + ch) * PSTRIDE + fc * 33;
    po[fp]      = ms;
    po[16 + fp] = vs;
    if (fp == 0) po[32] = rsc;
}

__global__ __launch_bounds__(512) void caps_fin(
    const float* __restrict__ pin,
    const float* __restrict__ bu,
    const float* __restrict__ ba,
    float* __restrict__ outp)
{
    const int tid = threadIdx.x;
    const int pos = blockIdx.x;
    const int fc = tid >> 4, fp = tid & 15;
    const float* q0 = pin + (size_t)pos * (NCH * PSTRIDE) + fc * 33;
    float ms = 0.f, vs = 0.f, rsc = 0.f;
    #pragma unroll
    for (int cc = 0; cc < NCH; ++cc) {
        const float* q = q0 + cc * PSTRIDE;
        ms  += q[fp];
        vs  += q[16 + fp];
        rsc += q[32];
    }
    const float inv = 1.f / (rsc + 1e-6f);
    const float S   = rsc * inv;
    const float mu  = ms * inv;
    const float sig = vs * inv - mu * mu * (2.f - S) + 1e-6f;
    const float lg  = __logf(sig);
    float lgs = lg;
    #pragma unroll
    for (int msk = 8; msk >= 1; msk >>= 1) lgs += __shfl_xor(lgs, msk);
    const float cost = rsc * (16.f * bu[fc] + 0.5f * lgs);
    const float ao   = 1.f / (1.f + __expf(-0.001f * (ba[fc] - cost)));
    outp[(size_t)pos * 512 + tid] = mu;
    if (fp == 0) outp[147456 + (size_t)pos * 32 + fc] = ao;
}

// ---------------------------------------------------------------------------
// Fallback: previous single-kernel version (used only if workspace too small).
// ---------------------------------------------------------------------------
__global__ __launch_bounds__(TPB) void convcaps_kernel(
    const float* __restrict__ xg,
    const float* __restrict__ ag,
    const float* __restrict__ wg,
    const float* __restrict__ bu,
    const float* __restrict__ ba,
    float* __restrict__ outp)
{
    __shared__ __align__(16) float pose_s[4608];
    __shared__ float a_s[288];
    __shared__ __align__(16) float scratch[8448];
    __shared__ float rsum_part[256];
    __shared__ float mu_tab[512];
    __shared__ float i2s_tab[512];
    __shared__ float aout_tab[32];
    __shared__ float Kc_tab[32];

    const int tid = threadIdx.x;
    const int pos = blockIdx.x;
    const int bb  = pos / 36;
    const int rem = pos % 36;
    const int yy  = rem / 6;
    const int xx  = rem % 6;

    #pragma unroll
    for (int wi = 0; wi < 9; ++wi) {
        const int kh = wi / 3, kw = wi % 3;
        const float* src =
            xg + (size_t)((((bb * 14) + (2 * yy + kh)) * 14 + (2 * xx + kw)) * 32) * 16;
        pose_s[wi * 512 + tid] = src[tid];
    }
    if (tid < 288) {
        const int wi = tid >> 5, bi = tid & 31;
        const int kh = wi / 3, kw = wi % 3;
        a_s[tid] = ag[(size_t)(((bb * 14) + (2 * yy + kh)) * 14 + (2 * xx + kw)) * 32 + bi];
    }
    __syncthreads();

    const int c    = tid & 31;
    const int s    = tid >> 5;
    const int lane = tid & 63;
    const int wv   = tid >> 6;
    const float4* wp = (const float4*)wg;

    for (int it = 0; it < 3; ++it) {
        float mu_c[16], i2s_c[16], Kc = 0.f;
        if (it > 0) {
            #pragma unroll
            for (int p = 0; p < 16; ++p) {
                mu_c[p]  = mu_tab[c * 16 + p];
                i2s_c[p] = i2s_tab[c * 16 + p];
            }
            Kc = Kc_tab[c];
        }
        float macc[16], vacc[16], rs = 0.f;
        #pragma unroll
        for (int p = 0; p < 16; ++p) { macc[p] = 0.f; vacc[p] = 0.f; }

        for (int k = 0; k < 18; ++k) {
            const int n = s * 18 + k;
            const float4* pp = (const float4*)&pose_s[n << 4];
            float pf[16];
            float4 q;
            q = pp[0]; pf[0]=q.x; pf[1]=q.y; pf[2]=q.z;  pf[3]=q.w;
            q = pp[1]; pf[4]=q.x; pf[5]=q.y; pf[6]=q.z;  pf[7]=q.w;
            q = pp[2]; pf[8]=q.x; pf[9]=q.y; pf[10]=q.z; pf[11]=q.w;
            q = pp[3]; pf[12]=q.x; pf[13]=q.y; pf[14]=q.z; pf[15]=q.w;
            const int wbase = (n * 32 + c) * 4;
            float wf[16];
            float4 w0 = wp[wbase + 0]; wf[0]=w0.x;  wf[1]=w0.y;  wf[2]=w0.z;  wf[3]=w0.w;
            float4 w1 = wp[wbase + 1]; wf[4]=w1.x;  wf[5]=w1.y;  wf[6]=w1.z;  wf[7]=w1.w;
            float4 w2 = wp[wbase + 2]; wf[8]=w2.x;  wf[9]=w2.y;  wf[10]=w2.z; wf[11]=w2.w;
            float4 w3 = wp[wbase + 3]; wf[12]=w3.x; wf[13]=w3.y; wf[14]=w3.z; wf[15]=w3.w;
            float v[16];
            #pragma unroll
            for (int i = 0; i < 4; ++i)
                #pragma unroll
                for (int l = 0; l < 4; ++l)
                    v[i*4+l] = pf[i*4+0] * wf[0*4+l] + pf[i*4+1] * wf[1*4+l]
                             + pf[i*4+2] * wf[2*4+l] + pf[i*4+3] * wf[3*4+l];
            float r;
            if (it == 0) {
                r = a_s[n] * 0.03125f;
            } else {
                float t = 0.f;
                #pragma unroll
                for (int p = 0; p < 16; ++p) {
                    float d = v[p] - mu_c[p];
                    t = fmaf(d * d, i2s_c[p], t);
                }
                float lnap = -t - Kc;
                float m = lnap;
                #pragma unroll
                for (int msk = 16; msk >= 1; msk >>= 1) m = fmaxf(m, __shfl_xor(m, msk));
                float e = __expf(lnap - m);
                float sum = e;
                #pragma unroll
                for (int msk = 16; msk >= 1; msk >>= 1) sum += __shfl_xor(sum, msk);
                r = e / sum;
            }
            rs += r;
            #pragma unroll
            for (int p = 0; p < 16; ++p) {
                float rv = r * v[p];
                macc[p] += rv;
                vacc[p] = fmaf(rv, v[p], vacc[p]);
            }
        }

        #pragma unroll
        for (int p = 0; p < 16; ++p) {
            macc[p] += __shfl_xor(macc[p], 32);
            vacc[p] += __shfl_xor(vacc[p], 32);
        }
        rs += __shfl_xor(rs, 32);
        if (lane < 32) {
            const int base = (wv * 32 + lane) * 33;
            #pragma unroll
            for (int p = 0; p < 16; ++p) {
                scratch[base + p]      = macc[p];
                scratch[base + 16 + p] = vacc[p];
            }
            rsum_part[wv * 32 + lane] = rs;
        }
        __syncthreads();

        const int fc = tid >> 4, fp = tid & 15;
        float ms = 0.f, vs = 0.f, rsc = 0.f;
        #pragma unroll
        for (int w = 0; w < 8; ++w) {
            ms  += scratch[(w * 32 + fc) * 33 + fp];
            vs  += scratch[(w * 32 + fc) * 33 + 16 + fp];
            rsc += rsum_part[w * 32 + fc];
        }
        const float inv = 1.f / (rsc + 1e-6f);
        const float S   = rsc * inv;
        const float mu  = ms * inv;
        const float sig = vs * inv - mu * mu * (2.f - S) + 1e-6f;
        const float lg  = __logf(sig);
        float lgs = lg;
        #pragma unroll
        for (int msk = 8; msk >= 1; msk >>= 1) lgs += __shfl_xor(lgs, msk);
        const float buv  = bu[fc];
        const float bav  = ba[fc];
        const float cost = rsc * (16.f * buv + 0.5f * lgs);
        const float ao   = 1.f / (1.f + __expf(-0.001f * (bav - cost)));

        mu_tab[fc * 16 + fp]  = mu;
        i2s_tab[fc * 16 + fp] = 0.5f / sig;
        if (fp == 0) {
            aout_tab[fc] = ao;
            Kc_tab[fc]   = 0.5f * lgs - __logf(ao);
        }

        if (it == 2) {
            outp[(size_t)pos * 512 + tid] = mu;
            if (fp == 0) outp[147456 + (size_t)pos * 32 + fc] = ao;
        }
        __syncthreads();
    }
}

extern "C" void kernel_launch(void* const* d_in, const int* in_sizes, int n_in,
                              void* d_out, int out_size, void* d_ws, size_t ws_size,
                              hipStream_t stream) {
    (void)in_sizes; (void)n_in; (void)out_size;
    const float* x  = (const float*)d_in[0];
    const float* a  = (const float*)d_in[1];
    const float* w  = (const float*)d_in[2];
    const float* bu = (const float*)d_in[3];
    const float* ba = (const float*)d_in[4];
    float* out = (float*)d_out;

    const size_t buf_elems = (size_t)NPOS * NCH * PSTRIDE;
    if (ws_size < 2 * buf_elems * sizeof(float)) {
        // workspace too small for partials: fall back to single-kernel version
        convcaps_kernel<<<dim3(288), dim3(TPB), 0, stream>>>(x, a, w, bu, ba, out);
        return;
    }
    float* buf0 = (float*)d_ws;
    float* buf1 = buf0 + buf_elems;

    caps_acc<0><<<dim3(NPOS * NCH), dim3(APB), 0, stream>>>(x, a, w, bu, ba, nullptr, buf0);
    caps_acc<1><<<dim3(NPOS * NCH), dim3(APB), 0, stream>>>(x, a, w, bu, ba, buf0, buf1);
    caps_acc<2><<<dim3(NPOS * NCH), dim3(APB), 0, stream>>>(x, a, w, bu, ba, buf1, buf0);
    caps_fin<<<dim3(NPOS), dim3(512), 0, stream>>>(buf0, bu, ba, out);
}

// Round 2
// 134.097 us; speedup vs baseline: 1.5645x; 1.5645x over previous
//
#include <hip/hip_runtime.h>

#define TPB 512
#define APB 512
#define NPOS 288
#define NCH 3
#define CHUNK 96
#define PSTRIDE 1056  // 32 c * 33 floats (16 mu-acc, 16 var-acc, 1 rsum)

// ---------------------------------------------------------------------------
// Pipeline version: 3 accumulate kernels (one per EM iteration) + finalize.
// Grid 864 = 288 positions x 3 chunks of 96 n. Kernel boundaries provide the
// per-iteration global sync; chunk partials live in d_ws (no atomics).
// NOTE: no min-waves in __launch_bounds__ — forcing 4 waves/EU capped VGPR at
// 64 and spilled ~120 MB/dispatch to scratch (R1 post-mortem). The inner loop
// needs ~112 live VGPRs; let the allocator pick (~80 in the fused version).
// ---------------------------------------------------------------------------

template<int IT>
__global__ __launch_bounds__(APB) void caps_acc(
    const float* __restrict__ xg,
    const float* __restrict__ ag,
    const float* __restrict__ wg,
    const float* __restrict__ bu,
    const float* __restrict__ ba,
    const float* __restrict__ pin,   // previous-iteration partials (IT>0)
    float* __restrict__ pout)        // this-iteration partials
{
    __shared__ __align__(16) float pose_s[CHUNK * 16];   // 96 n x 16 p
    __shared__ float a_s[CHUNK];
    __shared__ __align__(16) float scratch[8 * 32 * 33]; // 8 waves x 32 c x 33
    __shared__ float rsum_part[8 * 32];
    __shared__ float mu_tab[512];
    __shared__ float i2s_tab[512];
    __shared__ float Kc_tab[32];

    const int tid = threadIdx.x;
    const int blk = blockIdx.x;
    const int pos = blk / NCH;
    const int ch  = blk - pos * NCH;     // kh row of the 3x3 window
    const int bb  = pos / 36;
    const int rem = pos % 36;
    const int yy  = rem / 6;
    const int xx  = rem % 6;

    // ---- stage this chunk's pose slice (window row kh=ch, kw=0..2) ----
    #pragma unroll
    for (int j = 0; j < 3; ++j) {
        const float* src =
            xg + (size_t)((((bb * 14) + (2 * yy + ch)) * 14 + (2 * xx + j)) * 32) * 16;
        pose_s[j * 512 + tid] = src[tid];
    }
    if (IT == 0) {
        if (tid < CHUNK) {
            const int j = tid >> 5, bi = tid & 31;
            a_s[tid] = ag[(size_t)(((bb * 14) + (2 * yy + ch)) * 14 + (2 * xx + j)) * 32 + bi];
        }
    }

    const int fc = tid >> 4, fp = tid & 15;
    if (IT > 0) {
        // ---- redundant finalize of previous iteration from global partials ----
        const float* q0 = pin + (size_t)pos * (NCH * PSTRIDE) + fc * 33;
        float ms = 0.f, vs = 0.f, rsc = 0.f;
        #pragma unroll
        for (int cc = 0; cc < NCH; ++cc) {
            const float* q = q0 + cc * PSTRIDE;
            ms  += q[fp];
            vs  += q[16 + fp];
            rsc += q[32];
        }
        const float inv = 1.f / (rsc + 1e-6f);
        const float S   = rsc * inv;
        const float mu  = ms * inv;
        const float sig = vs * inv - mu * mu * (2.f - S) + 1e-6f;
        const float lg  = __logf(sig);
        float lgs = lg;
        #pragma unroll
        for (int msk = 8; msk >= 1; msk >>= 1) lgs += __shfl_xor(lgs, msk);
        const float cost = rsc * (16.f * bu[fc] + 0.5f * lgs);
        const float ao   = 1.f / (1.f + __expf(-0.001f * (ba[fc] - cost)));
        mu_tab[tid]  = mu;            // tid == fc*16+fp
        i2s_tab[tid] = 0.5f / sig;
        if (fp == 0) Kc_tab[fc] = 0.5f * lgs - __logf(ao);
    }
    __syncthreads();

    const int c    = tid & 31;   // capsule-out index
    const int s    = tid >> 5;   // n-slice 0..15 (6 n each)
    const int lane = tid & 63;
    const int wv   = tid >> 6;
    const float4* wp = (const float4*)wg;

    float mu_c[16], i2s_c[16], Kc = 0.f;
    if (IT > 0) {
        #pragma unroll
        for (int p = 0; p < 16; ++p) {
            mu_c[p]  = mu_tab[c * 16 + p];
            i2s_c[p] = i2s_tab[c * 16 + p];
        }
        Kc = Kc_tab[c];
    }
    float macc[16], vacc[16], rs = 0.f;
    #pragma unroll
    for (int p = 0; p < 16; ++p) { macc[p] = 0.f; vacc[p] = 0.f; }

    // ---- fused E+M pass over this thread's 6 n values ----
    for (int k = 0; k < 6; ++k) {
        const int nl = s * 6 + k;            // 0..95 within chunk
        const int n  = ch * CHUNK + nl;      // global n
        const float4* pp = (const float4*)&pose_s[nl << 4];
        float pf[16];
        float4 q;
        q = pp[0]; pf[0]=q.x;  pf[1]=q.y;  pf[2]=q.z;  pf[3]=q.w;
        q = pp[1]; pf[4]=q.x;  pf[5]=q.y;  pf[6]=q.z;  pf[7]=q.w;
        q = pp[2]; pf[8]=q.x;  pf[9]=q.y;  pf[10]=q.z; pf[11]=q.w;
        q = pp[3]; pf[12]=q.x; pf[13]=q.y; pf[14]=q.z; pf[15]=q.w;
        const int wbase = (n * 32 + c) * 4;
        float wf[16];
        float4 w0 = wp[wbase + 0]; wf[0]=w0.x;  wf[1]=w0.y;  wf[2]=w0.z;  wf[3]=w0.w;
        float4 w1 = wp[wbase + 1]; wf[4]=w1.x;  wf[5]=w1.y;  wf[6]=w1.z;  wf[7]=w1.w;
        float4 w2 = wp[wbase + 2]; wf[8]=w2.x;  wf[9]=w2.y;  wf[10]=w2.z; wf[11]=w2.w;
        float4 w3 = wp[wbase + 3]; wf[12]=w3.x; wf[13]=w3.y; wf[14]=w3.z; wf[15]=w3.w;
        float v[16];
        #pragma unroll
        for (int i = 0; i < 4; ++i)
            #pragma unroll
            for (int l = 0; l < 4; ++l)
                v[i*4+l] = pf[i*4+0] * wf[0*4+l] + pf[i*4+1] * wf[1*4+l]
                         + pf[i*4+2] * wf[2*4+l] + pf[i*4+3] * wf[3*4+l];
        float r;
        if (IT == 0) {
            r = a_s[nl] * 0.03125f;  // (1/C) * a_in
        } else {
            // tree-reduced t = sum_p (v-mu)^2 * i2s
            float t0 = 0.f, t1 = 0.f, t2 = 0.f, t3 = 0.f;
            #pragma unroll
            for (int p = 0; p < 16; p += 4) {
                float d0 = v[p]   - mu_c[p];   t0 = fmaf(d0*d0, i2s_c[p],   t0);
                float d1 = v[p+1] - mu_c[p+1]; t1 = fmaf(d1*d1, i2s_c[p+1], t1);
                float d2 = v[p+2] - mu_c[p+2]; t2 = fmaf(d2*d2, i2s_c[p+2], t2);
                float d3 = v[p+3] - mu_c[p+3]; t3 = fmaf(d3*d3, i2s_c[p+3], t3);
            }
            float lnap = -((t0 + t1) + (t2 + t3)) - Kc;
            float m = lnap;
            #pragma unroll
            for (int msk = 16; msk >= 1; msk >>= 1) m = fmaxf(m, __shfl_xor(m, msk));
            float e = __expf(lnap - m);
            float sum = e;
            #pragma unroll
            for (int msk = 16; msk >= 1; msk >>= 1) sum += __shfl_xor(sum, msk);
            r = e / sum;
        }
        rs += r;
        #pragma unroll
        for (int p = 0; p < 16; ++p) {
            float rv = r * v[p];
            macc[p] += rv;
            vacc[p] = fmaf(rv, v[p], vacc[p]);
        }
    }

    // ---- reduce the 16 n-slices: shfl pairs, then LDS across 8 waves ----
    #pragma unroll
    for (int p = 0; p < 16; ++p) {
        macc[p] += __shfl_xor(macc[p], 32);
        vacc[p] += __shfl_xor(vacc[p], 32);
    }
    rs += __shfl_xor(rs, 32);
    if (lane < 32) {
        const int base = (wv * 32 + lane) * 33;
        #pragma unroll
        for (int p = 0; p < 16; ++p) {
            scratch[base + p]      = macc[p];
            scratch[base + 16 + p] = vacc[p];
        }
        rsum_part[wv * 32 + lane] = rs;
    }
    __syncthreads();

    // ---- block-level sum -> write chunk partials (not finalized) ----
    float ms = 0.f, vs = 0.f, rsc = 0.f;
    #pragma unroll
    for (int w = 0; w < 8; ++w) {
        ms  += scratch[(w * 32 + fc) * 33 + fp];
        vs  += scratch[(w * 32 + fc) * 33 + 16 + fp];
        rsc += rsum_part[w * 32 + fc];
    }
    float* po = pout + (size_t)(pos * NCH + ch) * PSTRIDE + fc * 33;
    po[fp]      = ms;
    po[16 + fp] = vs;
    if (fp == 0) po[32] = rsc;
}

__global__ __launch_bounds__(512) void caps_fin(
    const float* __restrict__ pin,
    const float* __restrict__ bu,
    const float* __restrict__ ba,
    float* __restrict__ outp)
{
    const int tid = threadIdx.x;
    const int pos = blockIdx.x;
    const int fc = tid >> 4, fp = tid & 15;
    const float* q0 = pin + (size_t)pos * (NCH * PSTRIDE) + fc * 33;
    float ms = 0.f, vs = 0.f, rsc = 0.f;
    #pragma unroll
    for (int cc = 0; cc < NCH; ++cc) {
        const float* q = q0 + cc * PSTRIDE;
        ms  += q[fp];
        vs  += q[16 + fp];
        rsc += q[32];
    }
    const float inv = 1.f / (rsc + 1e-6f);
    const float S   = rsc * inv;
    const float mu  = ms * inv;
    const float sig = vs * inv - mu * mu * (2.f - S) + 1e-6f;
    const float lg  = __logf(sig);
    float lgs = lg;
    #pragma unroll
    for (int msk = 8; msk >= 1; msk >>= 1) lgs += __shfl_xor(lgs, msk);
    const float cost = rsc * (16.f * bu[fc] + 0.5f * lgs);
    const float ao   = 1.f / (1.f + __expf(-0.001f * (ba[fc] - cost)));
    outp[(size_t)pos * 512 + tid] = mu;
    if (fp == 0) outp[147456 + (size_t)pos * 32 + fc] = ao;
}

// ---------------------------------------------------------------------------
// Fallback: previous single-kernel version (used only if workspace too small).
// ---------------------------------------------------------------------------
__global__ __launch_bounds__(TPB) void convcaps_kernel(
    const float* __restrict__ xg,
    const float* __restrict__ ag,
    const float* __restrict__ wg,
    const float* __restrict__ bu,
    const float* __restrict__ ba,
    float* __restrict__ outp)
{
    __shared__ __align__(16) float pose_s[4608];
    __shared__ float a_s[288];
    __shared__ __align__(16) float scratch[8448];
    __shared__ float rsum_part[256];
    __shared__ float mu_tab[512];
    __shared__ float i2s_tab[512];
    __shared__ float aout_tab[32];
    __shared__ float Kc_tab[32];

    const int tid = threadIdx.x;
    const int pos = blockIdx.x;
    const int bb  = pos / 36;
    const int rem = pos % 36;
    const int yy  = rem / 6;
    const int xx  = rem % 6;

    #pragma unroll
    for (int wi = 0; wi < 9; ++wi) {
        const int kh = wi / 3, kw = wi % 3;
        const float* src =
            xg + (size_t)((((bb * 14) + (2 * yy + kh)) * 14 + (2 * xx + kw)) * 32) * 16;
        pose_s[wi * 512 + tid] = src[tid];
    }
    if (tid < 288) {
        const int wi = tid >> 5, bi = tid & 31;
        const int kh = wi / 3, kw = wi % 3;
        a_s[tid] = ag[(size_t)(((bb * 14) + (2 * yy + kh)) * 14 + (2 * xx + kw)) * 32 + bi];
    }
    __syncthreads();

    const int c    = tid & 31;
    const int s    = tid >> 5;
    const int lane = tid & 63;
    const int wv   = tid >> 6;
    const float4* wp = (const float4*)wg;

    for (int it = 0; it < 3; ++it) {
        float mu_c[16], i2s_c[16], Kc = 0.f;
        if (it > 0) {
            #pragma unroll
            for (int p = 0; p < 16; ++p) {
                mu_c[p]  = mu_tab[c * 16 + p];
                i2s_c[p] = i2s_tab[c * 16 + p];
            }
            Kc = Kc_tab[c];
        }
        float macc[16], vacc[16], rs = 0.f;
        #pragma unroll
        for (int p = 0; p < 16; ++p) { macc[p] = 0.f; vacc[p] = 0.f; }

        for (int k = 0; k < 18; ++k) {
            const int n = s * 18 + k;
            const float4* pp = (const float4*)&pose_s[n << 4];
            float pf[16];
            float4 q;
            q = pp[0]; pf[0]=q.x; pf[1]=q.y; pf[2]=q.z;  pf[3]=q.w;
            q = pp[1]; pf[4]=q.x; pf[5]=q.y; pf[6]=q.z;  pf[7]=q.w;
            q = pp[2]; pf[8]=q.x; pf[9]=q.y; pf[10]=q.z; pf[11]=q.w;
            q = pp[3]; pf[12]=q.x; pf[13]=q.y; pf[14]=q.z; pf[15]=q.w;
            const int wbase = (n * 32 + c) * 4;
            float wf[16];
            float4 w0 = wp[wbase + 0]; wf[0]=w0.x;  wf[1]=w0.y;  wf[2]=w0.z;  wf[3]=w0.w;
            float4 w1 = wp[wbase + 1]; wf[4]=w1.x;  wf[5]=w1.y;  wf[6]=w1.z;  wf[7]=w1.w;
            float4 w2 = wp[wbase + 2]; wf[8]=w2.x;  wf[9]=w2.y;  wf[10]=w2.z; wf[11]=w2.w;
            float4 w3 = wp[wbase + 3]; wf[12]=w3.x; wf[13]=w3.y; wf[14]=w3.z; wf[15]=w3.w;
            float v[16];
            #pragma unroll
            for (int i = 0; i < 4; ++i)
                #pragma unroll
                for (int l = 0; l < 4; ++l)
                    v[i*4+l] = pf[i*4+0] * wf[0*4+l] + pf[i*4+1] * wf[1*4+l]
                             + pf[i*4+2] * wf[2*4+l] + pf[i*4+3] * wf[3*4+l];
            float r;
            if (it == 0) {
                r = a_s[n] * 0.03125f;
            } else {
                float t = 0.f;
                #pragma unroll
                for (int p = 0; p < 16; ++p) {
                    float d = v[p] - mu_c[p];
                    t = fmaf(d * d, i2s_c[p], t);
                }
                float lnap = -t - Kc;
                float m = lnap;
                #pragma unroll
                for (int msk = 16; msk >= 1; msk >>= 1) m = fmaxf(m, __shfl_xor(m, msk));
                float e = __expf(lnap - m);
                float sum = e;
                #pragma unroll
                for (int msk = 16; msk >= 1; msk >>= 1) sum += __shfl_xor(sum, msk);
                r = e / sum;
            }
            rs += r;
            #pragma unroll
            for (int p = 0; p < 16; ++p) {
                float rv = r * v[p];
                macc[p] += rv;
                vacc[p] = fmaf(rv, v[p], vacc[p]);
            }
        }

        #pragma unroll
        for (int p = 0; p < 16; ++p) {
            macc[p] += __shfl_xor(macc[p], 32);
            vacc[p] += __shfl_xor(vacc[p], 32);
        }
        rs += __shfl_xor(rs, 32);
        if (lane < 32) {
            const int base = (wv * 32 + lane) * 33;
            #pragma unroll
            for (int p = 0; p < 16; ++p) {
                scratch[base + p]      = macc[p];
                scratch[base + 16 + p] = vacc[p];
            }
            rsum_part[wv * 32 + lane] = rs;
        }
        __syncthreads();

        const int fc = tid >> 4, fp = tid & 15;
        float ms = 0.f, vs = 0.f, rsc = 0.f;
        #pragma unroll
        for (int w = 0; w < 8; ++w) {
            ms  += scratch[(w * 32 + fc) * 33 + fp];
            vs  += scratch[(w * 32 + fc) * 33 + 16 + fp];
            rsc += rsum_part[w * 32 + fc];
        }
        const float inv = 1.f / (rsc + 1e-6f);
        const float S   = rsc * inv;
        const float mu  = ms * inv;
        const float sig = vs * inv - mu * mu * (2.f - S) + 1e-6f;
        const float lg  = __logf(sig);
        float lgs = lg;
        #pragma unroll
        for (int msk = 8; msk >= 1; msk >>= 1) lgs += __shfl_xor(lgs, msk);
        const float buv  = bu[fc];
        const float bav  = ba[fc];
        const float cost = rsc * (16.f * buv + 0.5f * lgs);
        const float ao   = 1.f / (1.f + __expf(-0.001f * (bav - cost)));

        mu_tab[fc * 16 + fp]  = mu;
        i2s_tab[fc * 16 + fp] = 0.5f / sig;
        if (fp == 0) {
            aout_tab[fc] = ao;
            Kc_tab[fc]   = 0.5f * lgs - __logf(ao);
        }

        if (it == 2) {
            outp[(size_t)pos * 512 + tid] = mu;
            if (fp == 0) outp[147456 + (size_t)pos * 32 + fc] = ao;
        }
        __syncthreads();
    }
}

extern "C" void kernel_launch(void* const* d_in, const int* in_sizes, int n_in,
                              void* d_out, int out_size, void* d_ws, size_t ws_size,
                              hipStream_t stream) {
    (void)in_sizes; (void)n_in; (void)out_size;
    const float* x  = (const float*)d_in[0];
    const float* a  = (const float*)d_in[1];
    const float* w  = (const float*)d_in[2];
    const float* bu = (const float*)d_in[3];
    const float* ba = (const float*)d_in[4];
    float* out = (float*)d_out;

    const size_t buf_elems = (size_t)NPOS * NCH * PSTRIDE;
    if (ws_size < 2 * buf_elems * sizeof(float)) {
        // workspace too small for partials: fall back to single-kernel version
        convcaps_kernel<<<dim3(288), dim3(TPB), 0, stream>>>(x, a, w, bu, ba, out);
        return;
    }
    float* buf0 = (float*)d_ws;
    float* buf1 = buf0 + buf_elems;

    caps_acc<0><<<dim3(NPOS * NCH), dim3(APB), 0, stream>>>(x, a, w, bu, ba, nullptr, buf0);
    caps_acc<1><<<dim3(NPOS * NCH), dim3(APB), 0, stream>>>(x, a, w, bu, ba, buf0, buf1);
    caps_acc<2><<<dim3(NPOS * NCH), dim3(APB), 0, stream>>>(x, a, w, bu, ba, buf1, buf0);
    caps_fin<<<dim3(NPOS), dim3(512), 0, stream>>>(buf0, bu, ba, out);
}